// Round 14
// baseline (529.684 us; speedup 1.0000x reference)
//
#include <hip/hip_runtime.h>
#include <math.h>

#define NN_ 1024
#define DOUT_ 2112
#define NOUT_ 384

using f16x8_t = __attribute__((ext_vector_type(8))) _Float16;
using f32x4_t = __attribute__((ext_vector_type(4))) float;

// ---------------- K1: yraw[1024][1152] = in1 @ [wq|wkv|wqp|wkvp] + bias ----------------
__global__ __launch_bounds__(256) void k_gemm1(
    const float* __restrict__ in1,
    const float* __restrict__ wq, const float* __restrict__ bq,
    const float* __restrict__ wkv, const float* __restrict__ bkv,
    const float* __restrict__ wqp, const float* __restrict__ bqp,
    const float* __restrict__ wkvp, const float* __restrict__ bkvp,
    float* __restrict__ yraw)
{
    __shared__ float a_l[64 * 36];
    __shared__ float b_l[32 * 68];
    const int t = threadIdx.x;
    const int m0 = blockIdx.x * 64, j0 = blockIdx.y * 64;
    const int tx = t & 15, ty = t >> 4;
    float acc[4][4] = {};
    for (int k0 = 0; k0 < 384; k0 += 32) {
        #pragma unroll
        for (int e = 0; e < 2; ++e) {
            int idx = t + 256 * e;
            int r = idx >> 3, c4 = (idx & 7) * 4;
            *(float4*)&a_l[r * 36 + c4] = *(const float4*)&in1[(size_t)(m0 + r) * 384 + k0 + c4];
        }
        #pragma unroll
        for (int e = 0; e < 2; ++e) {
            int idx = t + 256 * e;
            int r = idx >> 4, c4 = (idx & 15) * 4;
            int j = j0 + c4;
            const float* w; int ncol, jj;
            if (j < 192)      { w = wq;   ncol = 192; jj = j; }
            else if (j < 576) { w = wkv;  ncol = 384; jj = j - 192; }
            else if (j < 720) { w = wqp;  ncol = 144; jj = j - 576; }
            else              { w = wkvp; ncol = 432; jj = j - 720; }
            *(float4*)&b_l[r * 68 + c4] = *(const float4*)&w[(size_t)(k0 + r) * ncol + jj];
        }
        __syncthreads();
        #pragma unroll 8
        for (int k = 0; k < 32; ++k) {
            float4 bv = *(const float4*)&b_l[k * 68 + tx * 4];
            #pragma unroll
            for (int i = 0; i < 4; ++i) {
                float av = a_l[(ty * 4 + i) * 36 + k];
                acc[i][0] += av * bv.x; acc[i][1] += av * bv.y;
                acc[i][2] += av * bv.z; acc[i][3] += av * bv.w;
            }
        }
        __syncthreads();
    }
    int j = j0 + tx * 4;
    float4 bias;
    {
        const float* b; int jj;
        if (j < 192)      { b = bq;   jj = j; }
        else if (j < 576) { b = bkv;  jj = j - 192; }
        else if (j < 720) { b = bqp;  jj = j - 576; }
        else              { b = bkvp; jj = j - 720; }
        bias = *(const float4*)&b[jj];
    }
    #pragma unroll
    for (int i = 0; i < 4; ++i) {
        float4 o;
        o.x = acc[i][0] + bias.x; o.y = acc[i][1] + bias.y;
        o.z = acc[i][2] + bias.z; o.w = acc[i][3] + bias.w;
        *(float4*)&yraw[(size_t)(m0 + ty * 4 + i) * 1152 + j] = o;
    }
}

// ---------------- K2: rotations + packing ----------------
// kpackT4: (j,m) at (j>>2)*4096 + 4m + (j&3); skT[h*1024+m]
// vP (fp16, octet-major): element (j, m) at ((m>>3)*512 + j)*8 + (m&7), j in [0,512):
//   j<192 vs(h*16+s); 192..479 vp(a*96+h*8+p); 480..511 zero.
//   MFMA B-frag load: lane(j=base+(ln&15), k-oct=ln>>4) -> addr ((m0/8+oct)*512+j)*16B
//   => consecutive lanes = consecutive 16B (coalesced), fixes the 64-scattered-lines/instr
//   pattern that made resF L2-request-bound (round-13 analysis).
__global__ __launch_bounds__(256) void k_rot(
    const float* __restrict__ yraw, const float* __restrict__ rotm, const float* __restrict__ trans,
    float* __restrict__ qp_arr, float* __restrict__ kpackT4, _Float16* __restrict__ vP,
    float* __restrict__ sq_arr, float* __restrict__ skT)
{
    __shared__ float rt_l[4][12];
    const int t = threadIdx.x;
    const int n0 = blockIdx.x * 4;
    if (t < 48) {
        int n_ = t / 12, i = t % 12;
        rt_l[n_][i] = (i < 9) ? rotm[(n0 + n_) * 9 + i] : trans[(n0 + n_) * 3 + (i - 9)];
    }
    __syncthreads();
    const int n_ = t >> 6, l = t & 63;
    const int n = n0 + n_;
    const float* y = yraw + (size_t)n * 1152;
    const float* R = rt_l[n_];
    const size_t vbase = ((size_t)(n >> 3) * 512) * 8 + (n & 7);
    #pragma unroll
    for (int jj = 0; jj < 9; ++jj) {
        int o = l + 64 * jj;
        if (o < 144) {
            int a = o / 48, kk = o % 48;
            float v = R[9 + a] + R[a*3+0] * y[576 + kk] + R[a*3+1] * y[576 + 48 + kk] + R[a*3+2] * y[576 + 96 + kk];
            qp_arr[(size_t)n * 144 + o] = v;
        } else if (o < 288) {
            int o2 = o - 144;
            int a = o2 / 48, r2 = o2 % 48;
            int kk = (r2 >> 2) * 12 + (r2 & 3);
            float v = R[9 + a] + R[a*3+0] * y[720 + kk] + R[a*3+1] * y[720 + 144 + kk] + R[a*3+2] * y[720 + 288 + kk];
            int j = 192 + o2;
            kpackT4[(size_t)(j >> 2) * 4096 + 4 * n + (j & 3)] = v;
        } else {
            int o3 = o - 288;
            int a = o3 / 96, r2 = o3 % 96;
            int kk = (r2 >> 3) * 12 + 4 + (r2 & 7);
            float v = R[9 + a] + R[a*3+0] * y[720 + kk] + R[a*3+1] * y[720 + 144 + kk] + R[a*3+2] * y[720 + 288 + kk];
            vP[vbase + (size_t)(192 + o3) * 8] = (_Float16)v;
        }
    }
    #pragma unroll
    for (int jj = 0; jj < 3; ++jj) {
        int o = l + 64 * jj;
        int h = o >> 4, r2 = o & 15;
        kpackT4[(size_t)(o >> 2) * 4096 + 4 * n + (o & 3)] = y[192 + h * 32 + r2];
        vP[vbase + (size_t)o * 8] = (_Float16)y[192 + h * 32 + 16 + r2];
    }
    if (l < 32) vP[vbase + (size_t)(480 + l) * 8] = (_Float16)0.f;
    if (l < 24) {
        int which = l / 12, h = l % 12;
        int base = (which == 0) ? 576 : 720;
        int stride = (which == 0) ? 48 : 144;
        float s = 0.f;
        #pragma unroll
        for (int a = 0; a < 3; ++a) {
            #pragma unroll
            for (int p = 0; p < 4; ++p) {
                int kk = (which == 0) ? (h * 4 + p) : (h * 12 + p);
                float v = R[9 + a] + R[a*3+0] * y[base + kk] + R[a*3+1] * y[base + stride + kk] + R[a*3+2] * y[base + 2 * stride + kk];
                s += v * v;
            }
        }
        if (which == 0) sq_arr[(size_t)n * 12 + h] = s;
        else            skT[(size_t)h * 1024 + n] = s;
    }
}

// ---------------- K3: fused flash IPA, one n/block, MT=64, MFMA at2+res2d+resF (fp16) ----
// plain __launch_bounds__(256): any min-waves hint caps VGPR at 64 and spills GBs (r3-5).
__global__ __launch_bounds__(256) void k_attn11(
    const float* __restrict__ x2d, const float* __restrict__ mask,
    const float* __restrict__ w2d, const float* __restrict__ b2d, const float* __restrict__ tpw,
    const float* __restrict__ yraw, const float* __restrict__ qp_arr,
    const float* __restrict__ kpackT4, const _Float16* __restrict__ vP,
    const float* __restrict__ sq_arr, const float* __restrict__ skT,
    const float* __restrict__ rotm, const float* __restrict__ trans,
    float* __restrict__ fin)
{
    __shared__ _Float16 x_lT[128][72];   // 18.4 KB [c][m]
    __shared__ _Float16 tlb[16][72];     // 2.3 KB P [h][m]; rows 12-15 zeroed
    __shared__ _Float16 w2bT[16][136];   // 4.4 KB W2^T [h][c], zero-padded
    __shared__ float at2_l[64][13];
    __shared__ float qs_l[192], qp_l[144];
    __shared__ float sq_l[12], pw_l[12], b2_l[12];
    __shared__ float rmax_l[12], rsum_l[16], alph_l[16];
    __shared__ float rt_l[12];
    __shared__ float pg_l[288];

    const int t = threadIdx.x;
    const int n = blockIdx.x;

    const int wv = t >> 6, ln = t & 63;    // wave, lane
    const int mmS = ln & 15, oS = ln >> 4; // A-frag: m-sub, c/k-octet
    const int m3 = t & 63, hg = t >> 6;    // logits: lane=m, wave=h-trio
    const int rowB = (ln >> 4) * 4;        // D rows this lane holds

    f32x4_t accM[2] = {{0.f,0.f,0.f,0.f},{0.f,0.f,0.f,0.f}};
    f32x4_t accF[8];
    #pragma unroll
    for (int jt = 0; jt < 8; ++jt) accF[jt] = (f32x4_t){0.f,0.f,0.f,0.f};
    f16x8_t afr[4];   // next-tile X A-frags (fp16, packed at prefetch)

    // ---- prologue ----
    for (int i = t; i < 2176; i += 256) {   // w2bT zero-padded
        int h = i / 136, c = i % 136;
        w2bT[h][c] = (h < 12 && c < 128) ? (_Float16)w2d[c * 12 + h] : (_Float16)0.f;
    }
    tlb[12 + (t >> 6)][t & 63] = (_Float16)0.f;   // zero garbage rows 12-15 (cols 0-63 used)
    if (t < 192) qs_l[t] = yraw[(size_t)n * 1152 + t];
    if (t < 144) qp_l[t] = qp_arr[(size_t)n * 144 + t];
    if (t < 12) {
        sq_l[t] = sq_arr[(size_t)n * 12 + t];
        pw_l[t] = 0.13608276348795434f * log1pf(__expf(tpw[t]));
        b2_l[t] = b2d[t];
        rmax_l[t] = -3.0e38f;
        rt_l[t] = (t < 9) ? rotm[n * 9 + t] : trans[n * 3 + (t - 9)];
    }
    if (t < 16) { rsum_l[t] = 0.f; alph_l[t] = 1.0f; }
    const float maskn = mask[n];

    {   // initial prefetch (tile 0): load fp32, pack to fp16 A-frags
        const float* xr = x2d + ((size_t)n * NN_ + wv * 16 + mmS) * 128 + oS * 8;
        #pragma unroll
        for (int kk = 0; kk < 4; ++kk) {
            float4 a = *(const float4*)&xr[kk * 32];
            float4 b = *(const float4*)&xr[kk * 32 + 4];
            f16x8_t f;
            f[0]=(_Float16)a.x; f[1]=(_Float16)a.y; f[2]=(_Float16)a.z; f[3]=(_Float16)a.w;
            f[4]=(_Float16)b.x; f[5]=(_Float16)b.y; f[6]=(_Float16)b.z; f[7]=(_Float16)b.w;
            afr[kk] = f;
        }
    }
    __syncthreads();

    for (int mt = 0; mt < 16; ++mt) {
        const int m0 = mt * 64;
        // ===== STAGE: afr -> x_lT + at2 via MFMA =====
        {
            const int m = wv * 16 + mmS;
            #pragma unroll
            for (int kk = 0; kk < 4; ++kk) {
                const int c0 = kk * 32 + oS * 8;
                #pragma unroll
                for (int i = 0; i < 8; ++i) x_lT[c0 + i][m] = afr[kk][i];
            }
            f32x4_t aA = {0.f, 0.f, 0.f, 0.f};
            #pragma unroll
            for (int kk = 0; kk < 4; ++kk) {
                f16x8_t bfW = *(const f16x8_t*)&w2bT[ln & 15][kk * 32 + (ln >> 4) * 8];
                aA = __builtin_amdgcn_mfma_f32_16x16x32_f16(afr[kk], bfW, aA, 0, 0, 0);
            }
            const int hC = ln & 15;
            if (hC < 12) {
                #pragma unroll
                for (int r = 0; r < 4; ++r)
                    at2_l[wv * 16 + (ln >> 4) * 4 + r][hC] = aA[r];
            }
        }
        __syncthreads();   // (1) x_lT / at2_l ready

        // ===== LOGITS + wave-internal online softmax; prefetch+pack next x =====
        {
            int m1 = (mt + 1 == 16) ? 0 : (m0 + 64);
            const float* xr = x2d + ((size_t)n * NN_ + m1 + wv * 16 + mmS) * 128 + oS * 8;
            #pragma unroll
            for (int kk = 0; kk < 4; ++kk) {
                float4 a = *(const float4*)&xr[kk * 32];
                float4 b = *(const float4*)&xr[kk * 32 + 4];
                f16x8_t f;
                f[0]=(_Float16)a.x; f[1]=(_Float16)a.y; f[2]=(_Float16)a.z; f[3]=(_Float16)a.w;
                f[4]=(_Float16)b.x; f[5]=(_Float16)b.y; f[6]=(_Float16)b.z; f[7]=(_Float16)b.w;
                afr[kk] = f;
            }
        }
        {
            const int mg = m0 + m3;
            const float* kb = kpackT4 + 4 * (size_t)mg;
            const float mko = 100000.0f * (1.0f - maskn * mask[mg]);
            #pragma unroll
            for (int e = 0; e < 3; ++e) {
                const int h = hg * 3 + e;
                float4 k0 = *(const float4*)&kb[(size_t)(h * 4 + 0) * 4096];
                float4 k1 = *(const float4*)&kb[(size_t)(h * 4 + 1) * 4096];
                float4 k2 = *(const float4*)&kb[(size_t)(h * 4 + 2) * 4096];
                float4 k3 = *(const float4*)&kb[(size_t)(h * 4 + 3) * 4096];
                float4 p0 = *(const float4*)&kb[(size_t)(48 + h) * 4096];
                float4 p1 = *(const float4*)&kb[(size_t)(60 + h) * 4096];
                float4 p2 = *(const float4*)&kb[(size_t)(72 + h) * 4096];
                float skm = skT[(size_t)h * 1024 + mg];
                const float4* qsn = (const float4*)&qs_l[h * 16];
                float dqs = qsn[0].x*k0.x + qsn[0].y*k0.y + qsn[0].z*k0.z + qsn[0].w*k0.w
                          + qsn[1].x*k1.x + qsn[1].y*k1.y + qsn[1].z*k1.z + qsn[1].w*k1.w
                          + qsn[2].x*k2.x + qsn[2].y*k2.y + qsn[2].z*k2.z + qsn[2].w*k2.w
                          + qsn[3].x*k3.x + qsn[3].y*k3.y + qsn[3].z*k3.z + qsn[3].w*k3.w;
                float4 qA = *(const float4*)&qp_l[h * 4];
                float4 qB = *(const float4*)&qp_l[48 + h * 4];
                float4 qC = *(const float4*)&qp_l[96 + h * 4];
                float qk = qA.x*p0.x + qA.y*p0.y + qA.z*p0.z + qA.w*p0.w
                         + qB.x*p1.x + qB.y*p1.y + qB.z*p1.z + qB.w*p1.w
                         + qC.x*p2.x + qC.y*p2.y + qC.z*p2.z + qC.w*p2.w;
                float pwh = pw_l[h];
                float lg = 0.14433756729740643f * dqs
                         + pwh * qk - 0.5f * pwh * (sq_l[h] + skm)
                         + 0.57735026918962576f * (at2_l[m3][h] + b2_l[h])
                         - mko;
                float tm = lg;
                tm = fmaxf(tm, __shfl_xor(tm, 1));
                tm = fmaxf(tm, __shfl_xor(tm, 2));
                tm = fmaxf(tm, __shfl_xor(tm, 4));
                tm = fmaxf(tm, __shfl_xor(tm, 8));
                tm = fmaxf(tm, __shfl_xor(tm, 16));
                tm = fmaxf(tm, __shfl_xor(tm, 32));
                float om = rmax_l[h];
                float nm = fmaxf(om, tm);
                float p = __expf(lg - nm);
                tlb[h][m3] = (_Float16)p;
                float ps = p;
                ps += __shfl_xor(ps, 1);
                ps += __shfl_xor(ps, 2);
                ps += __shfl_xor(ps, 4);
                ps += __shfl_xor(ps, 8);
                ps += __shfl_xor(ps, 16);
                ps += __shfl_xor(ps, 32);
                if (m3 == 0) {
                    float al = __expf(om - nm);
                    rmax_l[h] = nm;
                    alph_l[h] = al;
                    rsum_l[h] = rsum_l[h] * al + ps;
                }
            }
        }
        __syncthreads();   // (2) tlb / alph ready

        // ===== ACCUM: res2d + resF via MFMA (vP octet-major: coalesced B-frags) =====
        {
            f32x4_t av = { alph_l[rowB], alph_l[rowB + 1], alph_l[rowB + 2], alph_l[rowB + 3] };
            accM[0] *= av;
            accM[1] *= av;
            #pragma unroll
            for (int jt = 0; jt < 8; ++jt) accF[jt] *= av;
            f16x8_t pA0 = *(const f16x8_t*)&tlb[ln & 15][(ln >> 4) * 8];
            f16x8_t pA1 = *(const f16x8_t*)&tlb[ln & 15][32 + (ln >> 4) * 8];
            #pragma unroll
            for (int nt = 0; nt < 2; ++nt) {
                int c = wv * 32 + nt * 16 + (ln & 15);
                f16x8_t xB0 = *(const f16x8_t*)&x_lT[c][(ln >> 4) * 8];
                f16x8_t xB1 = *(const f16x8_t*)&x_lT[c][32 + (ln >> 4) * 8];
                accM[nt] = __builtin_amdgcn_mfma_f32_16x16x32_f16(pA0, xB0, accM[nt], 0, 0, 0);
                accM[nt] = __builtin_amdgcn_mfma_f32_16x16x32_f16(pA1, xB1, accM[nt], 0, 0, 0);
            }
            const size_t o0 = (size_t)(m0 >> 3) + (ln >> 4);
            #pragma unroll
            for (int jt = 0; jt < 8; ++jt) {
                int j = (wv * 8 + jt) * 16 + (ln & 15);
                f16x8_t vB0 = *(const f16x8_t*)&vP[(o0 * 512 + j) * 8];
                f16x8_t vB1 = *(const f16x8_t*)&vP[((o0 + 4) * 512 + j) * 8];
                accF[jt] = __builtin_amdgcn_mfma_f32_16x16x32_f16(pA0, vB0, accF[jt], 0, 0, 0);
                accF[jt] = __builtin_amdgcn_mfma_f32_16x16x32_f16(pA1, vB1, accF[jt], 0, 0, 0);
            }
        }
        __syncthreads();   // (3) protect x_lT / tlb / at2_l for next tile
    }

    // ================= epilogue =================
    #pragma unroll
    for (int nt = 0; nt < 2; ++nt) {
        #pragma unroll
        for (int r = 0; r < 4; ++r) {
            int row = rowB + r;
            if (row < 12) {
                int c = wv * 32 + nt * 16 + (ln & 15);
                fin[(size_t)n * DOUT_ + 576 + (size_t)row * 128 + c] = accM[nt][r] / rsum_l[row];
            }
        }
    }
    #pragma unroll
    for (int jt = 0; jt < 8; ++jt) {
        int j = (wv * 8 + jt) * 16 + (ln & 15);
        if (j < 480) {
            int hj = (j < 192) ? (j >> 4) : (((j - 192) % 96) >> 3);
            if (hj >= rowB && hj < rowB + 4) {
                float val = accF[jt][hj - rowB] / rsum_l[hj];
                if (j < 192) fin[(size_t)n * DOUT_ + j] = val;
                else         pg_l[j - 192] = val;
            }
        }
    }
    __syncthreads();
    if (t < 96) {
        const int k = t;
        float c0 = pg_l[k]       - rt_l[9];
        float c1 = pg_l[96 + k]  - rt_l[10];
        float c2 = pg_l[192 + k] - rt_l[11];
        float r0 = rt_l[0] * c0 + rt_l[3] * c1 + rt_l[6] * c2;
        float r1 = rt_l[1] * c0 + rt_l[4] * c1 + rt_l[7] * c2;
        float r2 = rt_l[2] * c0 + rt_l[5] * c1 + rt_l[8] * c2;
        size_t base = (size_t)n * DOUT_;
        fin[base + 192 + k] = r0;
        fin[base + 288 + k] = r1;
        fin[base + 384 + k] = r2;
        fin[base + 480 + k] = sqrtf(1e-8f + r0 * r0 + r1 * r1 + r2 * r2);
    }
}

// ---------------- K5: out partials, split-K over 4 chunks of 528 ----------------
__global__ __launch_bounds__(256) void k_out(
    const float* __restrict__ fin, const float* __restrict__ wo,
    float* __restrict__ pout)
{
    __shared__ float a_l[64 * 52];
    __shared__ float b_l[48 * 68];
    const int t = threadIdx.x;
    const int m0 = blockIdx.x * 64, n0 = blockIdx.y * 64, kc = blockIdx.z;
    const int tx = t & 15, ty = t >> 4;
    float acc[4][4] = {};
    for (int k0 = kc * 528; k0 < kc * 528 + 528; k0 += 48) {
        #pragma unroll
        for (int e = 0; e < 3; ++e) {
            int idx = t + 256 * e;
            int r = idx / 12, c4 = (idx % 12) * 4;
            *(float4*)&a_l[r * 52 + c4] = *(const float4*)&fin[(size_t)(m0 + r) * DOUT_ + k0 + c4];
        }
        #pragma unroll
        for (int e = 0; e < 3; ++e) {
            int idx = t + 256 * e;
            int r = idx >> 4, c4 = (idx & 15) * 4;
            *(float4*)&b_l[r * 68 + c4] = *(const float4*)&wo[(size_t)(k0 + r) * 384 + n0 + c4];
        }
        __syncthreads();
        #pragma unroll 4
        for (int k = 0; k < 48; ++k) {
            float4 bv = *(const float4*)&b_l[k * 68 + tx * 4];
            #pragma unroll
            for (int i = 0; i < 4; ++i) {
                float av = a_l[(ty * 4 + i) * 52 + k];
                acc[i][0] += av * bv.x; acc[i][1] += av * bv.y;
                acc[i][2] += av * bv.z; acc[i][3] += av * bv.w;
            }
        }
        __syncthreads();
    }
    float* pr = pout + (size_t)kc * 393216;
    #pragma unroll
    for (int i = 0; i < 4; ++i) {
        float4 o;
        o.x = acc[i][0]; o.y = acc[i][1]; o.z = acc[i][2]; o.w = acc[i][3];
        *(float4*)&pr[(size_t)(m0 + ty * 4 + i) * 384 + n0 + tx * 4] = o;
    }
}

// ---------------- K6: sum split-K partials + bias ----------------
__global__ __launch_bounds__(256) void k_fin(
    const float* __restrict__ pout, const float* __restrict__ bo, float* __restrict__ out)
{
    int idx = blockIdx.x * 256 + threadIdx.x;
    float4 a = *(const float4*)&pout[(size_t)idx * 4];
    float4 b = *(const float4*)&pout[393216 + (size_t)idx * 4];
    float4 c = *(const float4*)&pout[786432 + (size_t)idx * 4];
    float4 d = *(const float4*)&pout[1179648 + (size_t)idx * 4];
    float4 bias = *(const float4*)&bo[(idx % 96) * 4];
    float4 o;
    o.x = a.x + b.x + c.x + d.x + bias.x;
    o.y = a.y + b.y + c.y + d.y + bias.y;
    o.z = a.z + b.z + c.z + d.z + bias.z;
    o.w = a.w + b.w + c.w + d.w + bias.w;
    *(float4*)&out[(size_t)idx * 4] = o;
}

extern "C" void kernel_launch(void* const* d_in, const int* in_sizes, int n_in,
                              void* d_out, int out_size, void* d_ws, size_t ws_size,
                              hipStream_t stream) {
    const float* in1   = (const float*)d_in[0];
    const float* x2d   = (const float*)d_in[1];
    const float* mask  = (const float*)d_in[2];
    const float* rotm  = (const float*)d_in[3];
    const float* trans = (const float*)d_in[4];
    const float* wq    = (const float*)d_in[5];
    const float* bq    = (const float*)d_in[6];
    const float* wkv   = (const float*)d_in[7];
    const float* bkv   = (const float*)d_in[8];
    const float* wqp   = (const float*)d_in[9];
    const float* bqp   = (const float*)d_in[10];
    const float* wkvp  = (const float*)d_in[11];
    const float* bkvp  = (const float*)d_in[12];
    const float* w2d   = (const float*)d_in[13];
    const float* b2d   = (const float*)d_in[14];
    const float* tpw   = (const float*)d_in[15];
    const float* wo    = (const float*)d_in[16];
    const float* bo    = (const float*)d_in[17];
    float* out = (float*)d_out;

    float* ws = (float*)d_ws;
    float* yraw    = ws;                    // 1,179,648
    float* qp_arr  = yraw + 1179648;        //   147,456
    float* kpackT4 = qp_arr + 147456;       //   360,448
    float* vP_f    = kpackT4 + 360448;      //   262,144 (128 oct x 512 j x 8 fp16)
    float* sq_arr  = vP_f + 262144;         //    12,288
    float* fin     = sq_arr + 12288;        // 2,162,688
    float* pout    = fin + 2162688;         // 1,572,864
    float* skT     = pout + 1572864;        //    12,288
    _Float16* vP = (_Float16*)vP_f;

    hipLaunchKernelGGL(k_gemm1, dim3(16, 18), dim3(256), 0, stream,
        in1, wq, bq, wkv, bkv, wqp, bqp, wkvp, bkvp, yraw);
    hipLaunchKernelGGL(k_rot, dim3(256), dim3(256), 0, stream,
        yraw, rotm, trans, qp_arr, kpackT4, vP, sq_arr, skT);
    hipLaunchKernelGGL(k_attn11, dim3(1024), dim3(256), 0, stream,
        x2d, mask, w2d, b2d, tpw, yraw, qp_arr, kpackT4, vP, sq_arr, skT, rotm, trans, fin);
    hipLaunchKernelGGL(k_out, dim3(16, 6, 4), dim3(256), 0, stream, fin, wo, pout);
    hipLaunchKernelGGL(k_fin, dim3(384), dim3(256), 0, stream, pout, bo, out);
}

// Round 15
// 344.105 us; speedup vs baseline: 1.5393x; 1.5393x over previous
//
#include <hip/hip_runtime.h>
#include <math.h>

#define NN_ 1024
#define DOUT_ 2112
#define NOUT_ 384

using f16x8_t = __attribute__((ext_vector_type(8))) _Float16;
using f16x4_t = __attribute__((ext_vector_type(4))) _Float16;
using f16x2_t = __attribute__((ext_vector_type(2))) _Float16;
using f32x4_t = __attribute__((ext_vector_type(4))) float;

#if __has_builtin(__builtin_amdgcn_fdot2)
#define DOT2(a, b, c) __builtin_amdgcn_fdot2((a), (b), (c), false)
#else
static __device__ __forceinline__ float DOT2(f16x2_t a, f16x2_t b, float c) {
    return c + (float)a[0] * (float)b[0] + (float)a[1] * (float)b[1];
}
#endif

// ---------------- K1: yraw[1024][1152] = in1 @ [wq|wkv|wqp|wkvp] + bias ----------------
__global__ __launch_bounds__(256) void k_gemm1(
    const float* __restrict__ in1,
    const float* __restrict__ wq, const float* __restrict__ bq,
    const float* __restrict__ wkv, const float* __restrict__ bkv,
    const float* __restrict__ wqp, const float* __restrict__ bqp,
    const float* __restrict__ wkvp, const float* __restrict__ bkvp,
    float* __restrict__ yraw)
{
    __shared__ float a_l[64 * 36];
    __shared__ float b_l[32 * 68];
    const int t = threadIdx.x;
    const int m0 = blockIdx.x * 64, j0 = blockIdx.y * 64;
    const int tx = t & 15, ty = t >> 4;
    float acc[4][4] = {};
    for (int k0 = 0; k0 < 384; k0 += 32) {
        #pragma unroll
        for (int e = 0; e < 2; ++e) {
            int idx = t + 256 * e;
            int r = idx >> 3, c4 = (idx & 7) * 4;
            *(float4*)&a_l[r * 36 + c4] = *(const float4*)&in1[(size_t)(m0 + r) * 384 + k0 + c4];
        }
        #pragma unroll
        for (int e = 0; e < 2; ++e) {
            int idx = t + 256 * e;
            int r = idx >> 4, c4 = (idx & 15) * 4;
            int j = j0 + c4;
            const float* w; int ncol, jj;
            if (j < 192)      { w = wq;   ncol = 192; jj = j; }
            else if (j < 576) { w = wkv;  ncol = 384; jj = j - 192; }
            else if (j < 720) { w = wqp;  ncol = 144; jj = j - 576; }
            else              { w = wkvp; ncol = 432; jj = j - 720; }
            *(float4*)&b_l[r * 68 + c4] = *(const float4*)&w[(size_t)(k0 + r) * ncol + jj];
        }
        __syncthreads();
        #pragma unroll 8
        for (int k = 0; k < 32; ++k) {
            float4 bv = *(const float4*)&b_l[k * 68 + tx * 4];
            #pragma unroll
            for (int i = 0; i < 4; ++i) {
                float av = a_l[(ty * 4 + i) * 36 + k];
                acc[i][0] += av * bv.x; acc[i][1] += av * bv.y;
                acc[i][2] += av * bv.z; acc[i][3] += av * bv.w;
            }
        }
        __syncthreads();
    }
    int j = j0 + tx * 4;
    float4 bias;
    {
        const float* b; int jj;
        if (j < 192)      { b = bq;   jj = j; }
        else if (j < 576) { b = bkv;  jj = j - 192; }
        else if (j < 720) { b = bqp;  jj = j - 576; }
        else              { b = bkvp; jj = j - 720; }
        bias = *(const float4*)&b[jj];
    }
    #pragma unroll
    for (int i = 0; i < 4; ++i) {
        float4 o;
        o.x = acc[i][0] + bias.x; o.y = acc[i][1] + bias.y;
        o.z = acc[i][2] + bias.z; o.w = acc[i][3] + bias.w;
        *(float4*)&yraw[(size_t)(m0 + ty * 4 + i) * 1152 + j] = o;
    }
}

// ---------------- K2: rotations + packing ----------------
// kpackH (fp16, octet-major): element (j,m) at ((j>>3)*1024 + m)*8 + (j&7), j in [0,336):
//   j<192 = ks (h*16+s); j in [192,336) = kp (192 + a*48 + h*4 + p). Coalesced 16B/lane.
// skT[h*1024+m] fp32.
// vT (fp16): [j][m], j in [0,512): j<192 vs(h*16+s); 192..479 vp(a*96+h*8+p); 480+ zero.
__global__ __launch_bounds__(256) void k_rot(
    const float* __restrict__ yraw, const float* __restrict__ rotm, const float* __restrict__ trans,
    float* __restrict__ qp_arr, _Float16* __restrict__ kpackH, _Float16* __restrict__ vT,
    float* __restrict__ sq_arr, float* __restrict__ skT)
{
    __shared__ float rt_l[4][12];
    const int t = threadIdx.x;
    const int n0 = blockIdx.x * 4;
    if (t < 48) {
        int n_ = t / 12, i = t % 12;
        rt_l[n_][i] = (i < 9) ? rotm[(n0 + n_) * 9 + i] : trans[(n0 + n_) * 3 + (i - 9)];
    }
    __syncthreads();
    const int n_ = t >> 6, l = t & 63;
    const int n = n0 + n_;
    const float* y = yraw + (size_t)n * 1152;
    const float* R = rt_l[n_];
    #pragma unroll
    for (int jj = 0; jj < 9; ++jj) {
        int o = l + 64 * jj;
        if (o < 144) {
            int a = o / 48, kk = o % 48;
            float v = R[9 + a] + R[a*3+0] * y[576 + kk] + R[a*3+1] * y[576 + 48 + kk] + R[a*3+2] * y[576 + 96 + kk];
            qp_arr[(size_t)n * 144 + o] = v;
        } else if (o < 288) {
            int o2 = o - 144;
            int a = o2 / 48, r2 = o2 % 48;
            int kk = (r2 >> 2) * 12 + (r2 & 3);
            float v = R[9 + a] + R[a*3+0] * y[720 + kk] + R[a*3+1] * y[720 + 144 + kk] + R[a*3+2] * y[720 + 288 + kk];
            int j = 192 + o2;
            kpackH[((size_t)(j >> 3) * 1024 + n) * 8 + (j & 7)] = (_Float16)v;
        } else {
            int o3 = o - 288;
            int a = o3 / 96, r2 = o3 % 96;
            int kk = (r2 >> 3) * 12 + 4 + (r2 & 7);
            float v = R[9 + a] + R[a*3+0] * y[720 + kk] + R[a*3+1] * y[720 + 144 + kk] + R[a*3+2] * y[720 + 288 + kk];
            vT[(size_t)(192 + o3) * 1024 + n] = (_Float16)v;
        }
    }
    #pragma unroll
    for (int jj = 0; jj < 3; ++jj) {
        int o = l + 64 * jj;
        int h = o >> 4, r2 = o & 15;
        kpackH[((size_t)(o >> 3) * 1024 + n) * 8 + (o & 7)] = (_Float16)y[192 + h * 32 + r2];
        vT[(size_t)o * 1024 + n] = (_Float16)y[192 + h * 32 + 16 + r2];
    }
    if (l < 32) vT[(size_t)(480 + l) * 1024 + n] = (_Float16)0.f;
    if (l < 24) {
        int which = l / 12, h = l % 12;
        int base = (which == 0) ? 576 : 720;
        int stride = (which == 0) ? 48 : 144;
        float s = 0.f;
        #pragma unroll
        for (int a = 0; a < 3; ++a) {
            #pragma unroll
            for (int p = 0; p < 4; ++p) {
                int kk = (which == 0) ? (h * 4 + p) : (h * 12 + p);
                float v = R[9 + a] + R[a*3+0] * y[base + kk] + R[a*3+1] * y[base + stride + kk] + R[a*3+2] * y[base + 2 * stride + kk];
                s += v * v;
            }
        }
        if (which == 0) sq_arr[(size_t)n * 12 + h] = s;
        else            skT[(size_t)h * 1024 + n] = s;
    }
}

// ---------------- K3: fused flash IPA, one n/block, MT=64, MFMA at2+res2d+resF (fp16) ----
// plain __launch_bounds__(256): any min-waves hint caps VGPR at 64 and spills GBs (r3-5).
// K is fp16 (kpackH) + fdot2 logits: halves K L2 traffic AND K-data register footprint
// (28->14 VGPR in logits peak) -- VGPR must stay <=128 (r14: 140 -> 3 waves/SIMD -> +40%).
__global__ __launch_bounds__(256) void k_attn12(
    const float* __restrict__ x2d, const float* __restrict__ mask,
    const float* __restrict__ w2d, const float* __restrict__ b2d, const float* __restrict__ tpw,
    const float* __restrict__ yraw, const float* __restrict__ qp_arr,
    const _Float16* __restrict__ kpackH, const _Float16* __restrict__ vT,
    const float* __restrict__ sq_arr, const float* __restrict__ skT,
    const float* __restrict__ rotm, const float* __restrict__ trans,
    float* __restrict__ fin)
{
    __shared__ _Float16 x_lT[128][72];   // 18.4 KB [c][m]
    __shared__ _Float16 tlb[16][72];     // 2.3 KB P [h][m]; rows 12-15 zeroed
    __shared__ _Float16 w2bT[16][136];   // 4.4 KB W2^T [h][c], zero-padded
    __shared__ float at2_l[64][13];
    __shared__ _Float16 qsh[12][16];     // Q-scalar fp16
    __shared__ _Float16 qph[144];        // Q-point fp16
    __shared__ float sq_l[12], pw_l[12], b2_l[12];
    __shared__ float rmax_l[12], rsum_l[16], alph_l[16];
    __shared__ float rt_l[12];
    __shared__ float pg_l[288];

    const int t = threadIdx.x;
    const int n = blockIdx.x;

    const int wv = t >> 6, ln = t & 63;    // wave, lane
    const int mmS = ln & 15, oS = ln >> 4; // A-frag: m-sub, c/k-octet
    const int m3 = t & 63, hg = t >> 6;    // logits: lane=m, wave=h-trio
    const int rowB = (ln >> 4) * 4;        // D rows this lane holds

    f32x4_t accM[2] = {{0.f,0.f,0.f,0.f},{0.f,0.f,0.f,0.f}};
    f32x4_t accF[8];
    #pragma unroll
    for (int jt = 0; jt < 8; ++jt) accF[jt] = (f32x4_t){0.f,0.f,0.f,0.f};
    f16x8_t afr[4];   // next-tile X A-frags (fp16, packed at prefetch)

    // ---- prologue ----
    for (int i = t; i < 2176; i += 256) {   // w2bT zero-padded
        int h = i / 136, c = i % 136;
        w2bT[h][c] = (h < 12 && c < 128) ? (_Float16)w2d[c * 12 + h] : (_Float16)0.f;
    }
    tlb[12 + (t >> 6)][t & 63] = (_Float16)0.f;   // zero garbage rows 12-15 (cols 0-63 used)
    if (t < 192) qsh[t >> 4][t & 15] = (_Float16)yraw[(size_t)n * 1152 + t];
    if (t < 144) qph[t] = (_Float16)qp_arr[(size_t)n * 144 + t];
    if (t < 12) {
        sq_l[t] = sq_arr[(size_t)n * 12 + t];
        pw_l[t] = 0.13608276348795434f * log1pf(__expf(tpw[t]));
        b2_l[t] = b2d[t];
        rmax_l[t] = -3.0e38f;
        rt_l[t] = (t < 9) ? rotm[n * 9 + t] : trans[n * 3 + (t - 9)];
    }
    if (t < 16) { rsum_l[t] = 0.f; alph_l[t] = 1.0f; }
    const float maskn = mask[n];

    {   // initial prefetch (tile 0): load fp32, pack to fp16 A-frags
        const float* xr = x2d + ((size_t)n * NN_ + wv * 16 + mmS) * 128 + oS * 8;
        #pragma unroll
        for (int kk = 0; kk < 4; ++kk) {
            float4 a = *(const float4*)&xr[kk * 32];
            float4 b = *(const float4*)&xr[kk * 32 + 4];
            f16x8_t f;
            f[0]=(_Float16)a.x; f[1]=(_Float16)a.y; f[2]=(_Float16)a.z; f[3]=(_Float16)a.w;
            f[4]=(_Float16)b.x; f[5]=(_Float16)b.y; f[6]=(_Float16)b.z; f[7]=(_Float16)b.w;
            afr[kk] = f;
        }
    }
    __syncthreads();

    for (int mt = 0; mt < 16; ++mt) {
        const int m0 = mt * 64;
        // ===== STAGE: afr -> x_lT + at2 via MFMA =====
        {
            const int m = wv * 16 + mmS;
            #pragma unroll
            for (int kk = 0; kk < 4; ++kk) {
                const int c0 = kk * 32 + oS * 8;
                #pragma unroll
                for (int i = 0; i < 8; ++i) x_lT[c0 + i][m] = afr[kk][i];
            }
            f32x4_t aA = {0.f, 0.f, 0.f, 0.f};
            #pragma unroll
            for (int kk = 0; kk < 4; ++kk) {
                f16x8_t bfW = *(const f16x8_t*)&w2bT[ln & 15][kk * 32 + (ln >> 4) * 8];
                aA = __builtin_amdgcn_mfma_f32_16x16x32_f16(afr[kk], bfW, aA, 0, 0, 0);
            }
            const int hC = ln & 15;
            if (hC < 12) {
                #pragma unroll
                for (int r = 0; r < 4; ++r)
                    at2_l[wv * 16 + (ln >> 4) * 4 + r][hC] = aA[r];
            }
        }
        __syncthreads();   // (1) x_lT / at2_l ready

        // ===== LOGITS + wave-internal online softmax; prefetch+pack next x =====
        {
            int m1 = (mt + 1 == 16) ? 0 : (m0 + 64);
            const float* xr = x2d + ((size_t)n * NN_ + m1 + wv * 16 + mmS) * 128 + oS * 8;
            #pragma unroll
            for (int kk = 0; kk < 4; ++kk) {
                float4 a = *(const float4*)&xr[kk * 32];
                float4 b = *(const float4*)&xr[kk * 32 + 4];
                f16x8_t f;
                f[0]=(_Float16)a.x; f[1]=(_Float16)a.y; f[2]=(_Float16)a.z; f[3]=(_Float16)a.w;
                f[4]=(_Float16)b.x; f[5]=(_Float16)b.y; f[6]=(_Float16)b.z; f[7]=(_Float16)b.w;
                afr[kk] = f;
            }
        }
        {
            const int mg = m0 + m3;
            const _Float16* kh = kpackH + (size_t)mg * 8;
            const float mko = 100000.0f * (1.0f - maskn * mask[mg]);
            #pragma unroll
            for (int e = 0; e < 3; ++e) {
                const int h = hg * 3 + e;
                f16x8_t ksA = *(const f16x8_t*)&kh[(size_t)(2 * h) * 8192];
                f16x8_t ksB = *(const f16x8_t*)&kh[(size_t)(2 * h + 1) * 8192];
                const int ja0 = 192 + h * 4, ja1 = 240 + h * 4, ja2 = 288 + h * 4;
                f16x4_t kpA = *(const f16x4_t*)&kh[(size_t)(ja0 >> 3) * 8192 + (ja0 & 7)];
                f16x4_t kpB = *(const f16x4_t*)&kh[(size_t)(ja1 >> 3) * 8192 + (ja1 & 7)];
                f16x4_t kpC = *(const f16x4_t*)&kh[(size_t)(ja2 >> 3) * 8192 + (ja2 & 7)];
                float skm = skT[(size_t)h * 1024 + mg];
                const f16x2_t* q2 = (const f16x2_t*)&qsh[h][0];
                float d = 0.f;
                #pragma unroll
                for (int i = 0; i < 4; ++i) {
                    f16x2_t ka = { ksA[2*i], ksA[2*i+1] };
                    d = DOT2(ka, q2[i], d);
                }
                #pragma unroll
                for (int i = 0; i < 4; ++i) {
                    f16x2_t kb2 = { ksB[2*i], ksB[2*i+1] };
                    d = DOT2(kb2, q2[4 + i], d);
                }
                float qk = 0.f;
                const f16x2_t* qpA = (const f16x2_t*)&qph[h * 4];
                const f16x2_t* qpB = (const f16x2_t*)&qph[48 + h * 4];
                const f16x2_t* qpC = (const f16x2_t*)&qph[96 + h * 4];
                {
                    f16x2_t a0 = { kpA[0], kpA[1] }, a1 = { kpA[2], kpA[3] };
                    f16x2_t b0 = { kpB[0], kpB[1] }, b1 = { kpB[2], kpB[3] };
                    f16x2_t c0 = { kpC[0], kpC[1] }, c1 = { kpC[2], kpC[3] };
                    qk = DOT2(a0, qpA[0], qk); qk = DOT2(a1, qpA[1], qk);
                    qk = DOT2(b0, qpB[0], qk); qk = DOT2(b1, qpB[1], qk);
                    qk = DOT2(c0, qpC[0], qk); qk = DOT2(c1, qpC[1], qk);
                }
                float pwh = pw_l[h];
                float lg = 0.14433756729740643f * d
                         + pwh * qk - 0.5f * pwh * (sq_l[h] + skm)
                         + 0.57735026918962576f * (at2_l[m3][h] + b2_l[h])
                         - mko;
                float tm = lg;
                tm = fmaxf(tm, __shfl_xor(tm, 1));
                tm = fmaxf(tm, __shfl_xor(tm, 2));
                tm = fmaxf(tm, __shfl_xor(tm, 4));
                tm = fmaxf(tm, __shfl_xor(tm, 8));
                tm = fmaxf(tm, __shfl_xor(tm, 16));
                tm = fmaxf(tm, __shfl_xor(tm, 32));
                float om = rmax_l[h];
                float nm = fmaxf(om, tm);
                float p = __expf(lg - nm);
                tlb[h][m3] = (_Float16)p;
                float ps = p;
                ps += __shfl_xor(ps, 1);
                ps += __shfl_xor(ps, 2);
                ps += __shfl_xor(ps, 4);
                ps += __shfl_xor(ps, 8);
                ps += __shfl_xor(ps, 16);
                ps += __shfl_xor(ps, 32);
                if (m3 == 0) {
                    float al = __expf(om - nm);
                    rmax_l[h] = nm;
                    alph_l[h] = al;
                    rsum_l[h] = rsum_l[h] * al + ps;
                }
            }
        }
        __syncthreads();   // (2) tlb / alph ready

        // ===== ACCUM: res2d + resF via MFMA =====
        {
            f32x4_t av = { alph_l[rowB], alph_l[rowB + 1], alph_l[rowB + 2], alph_l[rowB + 3] };
            accM[0] *= av;
            accM[1] *= av;
            #pragma unroll
            for (int jt = 0; jt < 8; ++jt) accF[jt] *= av;
            f16x8_t pA0 = *(const f16x8_t*)&tlb[ln & 15][(ln >> 4) * 8];
            f16x8_t pA1 = *(const f16x8_t*)&tlb[ln & 15][32 + (ln >> 4) * 8];
            #pragma unroll
            for (int nt = 0; nt < 2; ++nt) {
                int c = wv * 32 + nt * 16 + (ln & 15);
                f16x8_t xB0 = *(const f16x8_t*)&x_lT[c][(ln >> 4) * 8];
                f16x8_t xB1 = *(const f16x8_t*)&x_lT[c][32 + (ln >> 4) * 8];
                accM[nt] = __builtin_amdgcn_mfma_f32_16x16x32_f16(pA0, xB0, accM[nt], 0, 0, 0);
                accM[nt] = __builtin_amdgcn_mfma_f32_16x16x32_f16(pA1, xB1, accM[nt], 0, 0, 0);
            }
            const _Float16* vb = vT + (size_t)m0;
            #pragma unroll
            for (int jt = 0; jt < 8; ++jt) {
                int j = (wv * 8 + jt) * 16 + (ln & 15);
                f16x8_t vB0 = *(const f16x8_t*)&vb[(size_t)j * 1024 + (ln >> 4) * 8];
                f16x8_t vB1 = *(const f16x8_t*)&vb[(size_t)j * 1024 + 32 + (ln >> 4) * 8];
                accF[jt] = __builtin_amdgcn_mfma_f32_16x16x32_f16(pA0, vB0, accF[jt], 0, 0, 0);
                accF[jt] = __builtin_amdgcn_mfma_f32_16x16x32_f16(pA1, vB1, accF[jt], 0, 0, 0);
            }
        }
        __syncthreads();   // (3) protect x_lT / tlb / at2_l for next tile
    }

    // ================= epilogue =================
    #pragma unroll
    for (int nt = 0; nt < 2; ++nt) {
        #pragma unroll
        for (int r = 0; r < 4; ++r) {
            int row = rowB + r;
            if (row < 12) {
                int c = wv * 32 + nt * 16 + (ln & 15);
                fin[(size_t)n * DOUT_ + 576 + (size_t)row * 128 + c] = accM[nt][r] / rsum_l[row];
            }
        }
    }
    #pragma unroll
    for (int jt = 0; jt < 8; ++jt) {
        int j = (wv * 8 + jt) * 16 + (ln & 15);
        if (j < 480) {
            int hj = (j < 192) ? (j >> 4) : (((j - 192) % 96) >> 3);
            if (hj >= rowB && hj < rowB + 4) {
                float val = accF[jt][hj - rowB] / rsum_l[hj];
                if (j < 192) fin[(size_t)n * DOUT_ + j] = val;
                else         pg_l[j - 192] = val;
            }
        }
    }
    __syncthreads();
    if (t < 96) {
        const int k = t;
        float c0 = pg_l[k]       - rt_l[9];
        float c1 = pg_l[96 + k]  - rt_l[10];
        float c2 = pg_l[192 + k] - rt_l[11];
        float r0 = rt_l[0] * c0 + rt_l[3] * c1 + rt_l[6] * c2;
        float r1 = rt_l[1] * c0 + rt_l[4] * c1 + rt_l[7] * c2;
        float r2 = rt_l[2] * c0 + rt_l[5] * c1 + rt_l[8] * c2;
        size_t base = (size_t)n * DOUT_;
        fin[base + 192 + k] = r0;
        fin[base + 288 + k] = r1;
        fin[base + 384 + k] = r2;
        fin[base + 480 + k] = sqrtf(1e-8f + r0 * r0 + r1 * r1 + r2 * r2);
    }
}

// ---------------- K5: out partials, split-K over 4 chunks of 528 ----------------
__global__ __launch_bounds__(256) void k_out(
    const float* __restrict__ fin, const float* __restrict__ wo,
    float* __restrict__ pout)
{
    __shared__ float a_l[64 * 52];
    __shared__ float b_l[48 * 68];
    const int t = threadIdx.x;
    const int m0 = blockIdx.x * 64, n0 = blockIdx.y * 64, kc = blockIdx.z;
    const int tx = t & 15, ty = t >> 4;
    float acc[4][4] = {};
    for (int k0 = kc * 528; k0 < kc * 528 + 528; k0 += 48) {
        #pragma unroll
        for (int e = 0; e < 3; ++e) {
            int idx = t + 256 * e;
            int r = idx / 12, c4 = (idx % 12) * 4;
            *(float4*)&a_l[r * 52 + c4] = *(const float4*)&fin[(size_t)(m0 + r) * DOUT_ + k0 + c4];
        }
        #pragma unroll
        for (int e = 0; e < 3; ++e) {
            int idx = t + 256 * e;
            int r = idx >> 4, c4 = (idx & 15) * 4;
            *(float4*)&b_l[r * 68 + c4] = *(const float4*)&wo[(size_t)(k0 + r) * 384 + n0 + c4];
        }
        __syncthreads();
        #pragma unroll 4
        for (int k = 0; k < 48; ++k) {
            float4 bv = *(const float4*)&b_l[k * 68 + tx * 4];
            #pragma unroll
            for (int i = 0; i < 4; ++i) {
                float av = a_l[(ty * 4 + i) * 52 + k];
                acc[i][0] += av * bv.x; acc[i][1] += av * bv.y;
                acc[i][2] += av * bv.z; acc[i][3] += av * bv.w;
            }
        }
        __syncthreads();
    }
    float* pr = pout + (size_t)kc * 393216;
    #pragma unroll
    for (int i = 0; i < 4; ++i) {
        float4 o;
        o.x = acc[i][0]; o.y = acc[i][1]; o.z = acc[i][2]; o.w = acc[i][3];
        *(float4*)&pr[(size_t)(m0 + ty * 4 + i) * 384 + n0 + tx * 4] = o;
    }
}

// ---------------- K6: sum split-K partials + bias ----------------
__global__ __launch_bounds__(256) void k_fin(
    const float* __restrict__ pout, const float* __restrict__ bo, float* __restrict__ out)
{
    int idx = blockIdx.x * 256 + threadIdx.x;
    float4 a = *(const float4*)&pout[(size_t)idx * 4];
    float4 b = *(const float4*)&pout[393216 + (size_t)idx * 4];
    float4 c = *(const float4*)&pout[786432 + (size_t)idx * 4];
    float4 d = *(const float4*)&pout[1179648 + (size_t)idx * 4];
    float4 bias = *(const float4*)&bo[(idx % 96) * 4];
    float4 o;
    o.x = a.x + b.x + c.x + d.x + bias.x;
    o.y = a.y + b.y + c.y + d.y + bias.y;
    o.z = a.z + b.z + c.z + d.z + bias.z;
    o.w = a.w + b.w + c.w + d.w + bias.w;
    *(float4*)&out[(size_t)idx * 4] = o;
}

extern "C" void kernel_launch(void* const* d_in, const int* in_sizes, int n_in,
                              void* d_out, int out_size, void* d_ws, size_t ws_size,
                              hipStream_t stream) {
    const float* in1   = (const float*)d_in[0];
    const float* x2d   = (const float*)d_in[1];
    const float* mask  = (const float*)d_in[2];
    const float* rotm  = (const float*)d_in[3];
    const float* trans = (const float*)d_in[4];
    const float* wq    = (const float*)d_in[5];
    const float* bq    = (const float*)d_in[6];
    const float* wkv   = (const float*)d_in[7];
    const float* bkv   = (const float*)d_in[8];
    const float* wqp   = (const float*)d_in[9];
    const float* bqp   = (const float*)d_in[10];
    const float* wkvp  = (const float*)d_in[11];
    const float* bkvp  = (const float*)d_in[12];
    const float* w2d   = (const float*)d_in[13];
    const float* b2d   = (const float*)d_in[14];
    const float* tpw   = (const float*)d_in[15];
    const float* wo    = (const float*)d_in[16];
    const float* bo    = (const float*)d_in[17];
    float* out = (float*)d_out;

    float* ws = (float*)d_ws;
    float* yraw    = ws;                    // 1,179,648
    float* qp_arr  = yraw + 1179648;        //   147,456
    float* kpackH_f= qp_arr + 147456;       //   172,032 (42 oct x 1024 m x 8 fp16)
    float* vT_f    = kpackH_f + 172032;     //   262,144 (512 x 1024 fp16)
    float* sq_arr  = vT_f + 262144;         //    12,288
    float* fin     = sq_arr + 12288;        // 2,162,688
    float* pout    = fin + 2162688;         // 1,572,864
    float* skT     = pout + 1572864;        //    12,288
    _Float16* kpackH = (_Float16*)kpackH_f;
    _Float16* vT = (_Float16*)vT_f;

    hipLaunchKernelGGL(k_gemm1, dim3(16, 18), dim3(256), 0, stream,
        in1, wq, bq, wkv, bkv, wqp, bqp, wkvp, bkvp, yraw);
    hipLaunchKernelGGL(k_rot, dim3(256), dim3(256), 0, stream,
        yraw, rotm, trans, qp_arr, kpackH, vT, sq_arr, skT);
    hipLaunchKernelGGL(k_attn12, dim3(1024), dim3(256), 0, stream,
        x2d, mask, w2d, b2d, tpw, yraw, qp_arr, kpackH, vT, sq_arr, skT, rotm, trans, fin);
    hipLaunchKernelGGL(k_out, dim3(16, 6, 4), dim3(256), 0, stream, fin, wo, pout);
    hipLaunchKernelGGL(k_fin, dim3(384), dim3(256), 0, stream, pout, bo, out);
}